// Round 6
// baseline (27.849 us; speedup 1.0000x reference)
//
#include <hip/hip_runtime.h>

#define NPTS 512
#define DIM  128
#define EPSF 1e-16f
#define FIXSCALE 1048576.0f   // 2^20 fixed-point scale for the packed sum

// ---------------------------------------------------------------------------
// Single fused kernel: distance rows + triplet accumulation + atomic finalize.
// Grid: 256 blocks x 512 threads; block b handles anchors i0=2b, 2b+1.
//
// Cross-block finalize uses DEVICE-SCOPE ATOMICS ONLY (no __threadfence — that
// caused a ~38us L2-writeback storm across XCDs in an earlier round):
//   accA (u64) = [blocks_done:16 | sum_fixed:48]   (sum scaled by 2^20)
//   accB (u64) = count
// Each block: atomicAdd(accB, cnt) -> force completion (consume return value)
// -> atomicAdd(accA, (1<<48)+sfix). The block seeing done==255 in accA's old
// value knows ALL count-adds completed (per-block program order enforced by
// the vmcnt wait), reads accB atomically, writes out. Integer adds are
// order-independent -> bitwise-deterministic result.
// accA/accB zeroed by a 16B hipMemsetAsync captured in the same graph.
// ---------------------------------------------------------------------------
__global__ __launch_bounds__(512) void triplet_fused(
    const float* __restrict__ X,
    const int* __restrict__ labels,
    const float* __restrict__ bias,
    unsigned long long* __restrict__ accA,
    unsigned long long* __restrict__ accB,
    float* __restrict__ out)
{
    __shared__ int      lab[NPTS];
    __shared__ float    drow[2][NPTS];
    __shared__ float4   xi4[2][DIM / 4];
    __shared__ int      poslist[2][96];
    __shared__ int      npos[2];
    __shared__ float    wsum[8];
    __shared__ unsigned wcnt[8];

    const int blk = blockIdx.x;
    const int t   = threadIdx.x;
    const int i0  = blk * 2;

    lab[t] = labels[t];
    if (t < 64) {               // stage the two anchor rows (32 float4 each)
        const int a = t >> 5, c4 = t & 31;
        xi4[a][c4] = reinterpret_cast<const float4*>(X + (size_t)(i0 + a) * DIM)[c4];
    }
    if (t < 2) npos[t] = 0;
    __syncthreads();

    const int jl = t >> 2;      // 0..127 : j within a 128-row quarter
    const int ch = t & 3;       // dim chunk (32 dims, interleaved float4 cols)

    // anchor fragments in registers
    float4 w0[8], w1[8];
#pragma unroll
    for (int m = 0; m < 8; ++m) { w0[m] = xi4[0][ch + 4 * m]; w1[m] = xi4[1][ch + 4 * m]; }

    // anchor norms via the same 4-lane butterfly
    float n0 = 0.f, n1 = 0.f;
#pragma unroll
    for (int m = 0; m < 8; ++m) {
        float4 a = w0[m], b = w1[m];
        n0 += a.x * a.x + a.y * a.y + a.z * a.z + a.w * a.w;
        n1 += b.x * b.x + b.y * b.y + b.z * b.z + b.w * b.w;
    }
    n0 += __shfl_xor(n0, 1); n0 += __shfl_xor(n0, 2);
    n1 += __shfl_xor(n1, 1); n1 += __shfl_xor(n1, 2);

    // distance rows: 4 quarters of 128 j's; row j read once, dotted vs both anchors
#pragma unroll
    for (int q = 0; q < 4; ++q) {
        const int j = q * 128 + jl;
        const float4* xj = reinterpret_cast<const float4*>(X + (size_t)j * DIM);
        float d0 = 0.f, d1 = 0.f, nj = 0.f;
#pragma unroll
        for (int m = 0; m < 8; ++m) {
            const float4 v = xj[ch + 4 * m];
            const float4 a = w0[m], b = w1[m];
            d0 += v.x * a.x + v.y * a.y + v.z * a.z + v.w * a.w;
            d1 += v.x * b.x + v.y * b.y + v.z * b.z + v.w * b.w;
            nj += v.x * v.x + v.y * v.y + v.z * v.z + v.w * v.w;
        }
        d0 += __shfl_xor(d0, 1); d0 += __shfl_xor(d0, 2);
        d1 += __shfl_xor(d1, 1); d1 += __shfl_xor(d1, 2);
        nj += __shfl_xor(nj, 1); nj += __shfl_xor(nj, 2);
        if (ch == 0) {
            const float r0 = fmaxf(n0 + nj - 2.f * d0, 0.f);
            const float r1 = fmaxf(n1 + nj - 2.f * d1, 0.f);
            drow[0][j] = (r0 == 0.f) ? EPSF : (sqrtf(r0 + EPSF) + EPSF);
            drow[1][j] = (r1 == 0.f) ? EPSF : (sqrtf(r1 + EPSF) + EPSF);
        }
    }
    __syncthreads();

    // positive lists (same label, j != anchor), then deterministic sort
    const int li0 = lab[i0], li1 = lab[i0 + 1];
    {
        const int j = t;
        if (lab[j] == li0 && j != i0)     { int q = atomicAdd(&npos[0], 1); poslist[0][q] = j; }
        if (lab[j] == li1 && j != i0 + 1) { int q = atomicAdd(&npos[1], 1); poslist[1][q] = j; }
    }
    __syncthreads();
    if (t < 2) {                // insertion sort (~8 entries)
        const int n = npos[t];
        for (int a2 = 1; a2 < n; ++a2) {
            int v = poslist[t][a2];
            int b2 = a2 - 1;
            while (b2 >= 0 && poslist[t][b2] > v) { poslist[t][b2 + 1] = poslist[t][b2]; --b2; }
            poslist[t][b2 + 1] = v;
        }
    }
    __syncthreads();

    // triplet accumulation: thread t owns negative candidate k = t
    const float bv = bias[0];
    float    lsum = 0.f;
    unsigned lcnt = 0u;
#pragma unroll
    for (int a = 0; a < 2; ++a) {
        const int    la = lab[i0 + a];
        const float* dr = &drow[a][0];
        if (lab[t] != la) {
            const float dik = dr[t];
            const int n = npos[a];
            for (int q = 0; q < n; ++q) {
                const float s = dr[poslist[a][q]] - dik + bv;   // poslist read = broadcast
                if (s > 0.f) { lsum += s; lcnt += (s > EPSF) ? 1u : 0u; }
            }
        }
    }

    // wave (64) shuffle reduce, then cross-wave
#pragma unroll
    for (int off = 32; off > 0; off >>= 1) {
        lsum += __shfl_down(lsum, off);
        lcnt += __shfl_down(lcnt, off);
    }
    if ((t & 63) == 0) { wsum[t >> 6] = lsum; wcnt[t >> 6] = lcnt; }
    __syncthreads();

    if (t == 0) {
        float s = 0.f; unsigned c = 0u;
#pragma unroll
        for (int w = 0; w < 8; ++w) { s += wsum[w]; c += wcnt[w]; }

        const unsigned long long sfix = (unsigned long long)llrintf(s * FIXSCALE);

        // 1) publish count (device-scope atomic, coherent point)
        unsigned long long oldb = atomicAdd(accB, (unsigned long long)c);
        asm volatile("" :: "v"(oldb));   // consume -> s_waitcnt vmcnt: count-add
                                         // completed before sum-add issues
        // 2) publish sum + done-ticket in one packed atomic
        const unsigned long long olda = atomicAdd(accA, (1ull << 48) + sfix);
        if ((olda >> 48) == 255ull) {    // last block: all accB adds complete
            const unsigned long long totS = (olda & ((1ull << 48) - 1)) + sfix;
            const unsigned long long totC = atomicAdd(accB, 0ull);  // atomic read
            out[0] = (float)((double)totS * (1.0 / 1048576.0))
                     / ((float)totC + 1e-16f);
        }
    }
}

extern "C" void kernel_launch(void* const* d_in, const int* in_sizes, int n_in,
                              void* d_out, int out_size, void* d_ws, size_t ws_size,
                              hipStream_t stream) {
    const float* X      = (const float*)d_in[0];
    const int*   labels = (const int*)d_in[1];
    const float* bias   = (const float*)d_in[2];
    float*       out    = (float*)d_out;

    unsigned long long* accA = (unsigned long long*)d_ws;
    unsigned long long* accB = accA + 1;

    hipMemsetAsync(d_ws, 0, 16, stream);   // zero accA/accB (graph-capturable)
    triplet_fused<<<256, 512, 0, stream>>>(X, labels, bias, accA, accB, out);
}

// Round 7
// 20.178 us; speedup vs baseline: 1.3802x; 1.3802x over previous
//
#include <hip/hip_runtime.h>

#define NPTS 512
#define DIM  128
#define EPSF 1e-16f

// ---------------------------------------------------------------------------
// Fused kernel: distance rows + triplet accumulation, no D materialization.
// Grid: 256 blocks x 512 threads; block b handles anchors i0=2b, 2b+1.
// Dot: 4 lanes per j (32 dims each via interleaved float4 cols) + shfl_xor
//      butterfly; the j-row is read once and dotted against BOTH anchors.
// Reference semantics: draw = relu(ni + nj - 2*dot);
//                      d = (draw==0) ? EPS : sqrt(draw+EPS)+EPS.
//
// NOTE (learned r3/r6): no cross-block fences, no same-address atomic chains —
// both cost more than a dispatch on gfx950 (non-coherent per-XCD L2s).
// Two dispatches is the safe minimum (d_ws state at the correctness call is
// unknown, so no init-free single-dispatch protocol exists).
// ---------------------------------------------------------------------------
__global__ __launch_bounds__(512) void triplet_fused(
    const float* __restrict__ X,
    const int* __restrict__ labels,
    const float* __restrict__ bias,
    float* __restrict__ psum,
    unsigned* __restrict__ pcnt)
{
    __shared__ int      lab[NPTS];
    __shared__ float    drow[2][NPTS];
    __shared__ float4   xi4[2][DIM / 4];
    __shared__ int      poslist[2][96];
    __shared__ int      npos[2];
    __shared__ float    wsum[8];
    __shared__ unsigned wcnt[8];

    const int blk = blockIdx.x;
    const int t   = threadIdx.x;
    const int i0  = blk * 2;

    lab[t] = labels[t];
    if (t < 64) {               // stage the two anchor rows (32 float4 each)
        const int a = t >> 5, c4 = t & 31;
        xi4[a][c4] = reinterpret_cast<const float4*>(X + (size_t)(i0 + a) * DIM)[c4];
    }
    if (t < 2) npos[t] = 0;
    __syncthreads();

    const int jl = t >> 2;      // 0..127 : j within a 128-row quarter
    const int ch = t & 3;       // dim chunk (32 dims, interleaved float4 cols)

    // anchor fragments in registers
    float4 w0[8], w1[8];
#pragma unroll
    for (int m = 0; m < 8; ++m) { w0[m] = xi4[0][ch + 4 * m]; w1[m] = xi4[1][ch + 4 * m]; }

    // anchor norms via the same 4-lane butterfly
    float n0 = 0.f, n1 = 0.f;
#pragma unroll
    for (int m = 0; m < 8; ++m) {
        float4 a = w0[m], b = w1[m];
        n0 += a.x * a.x + a.y * a.y + a.z * a.z + a.w * a.w;
        n1 += b.x * b.x + b.y * b.y + b.z * b.z + b.w * b.w;
    }
    n0 += __shfl_xor(n0, 1); n0 += __shfl_xor(n0, 2);
    n1 += __shfl_xor(n1, 1); n1 += __shfl_xor(n1, 2);

    // distance rows: 4 quarters of 128 j's; row j read once, dotted vs both anchors
#pragma unroll
    for (int q = 0; q < 4; ++q) {
        const int j = q * 128 + jl;
        const float4* xj = reinterpret_cast<const float4*>(X + (size_t)j * DIM);
        float d0 = 0.f, d1 = 0.f, nj = 0.f;
#pragma unroll
        for (int m = 0; m < 8; ++m) {
            const float4 v = xj[ch + 4 * m];
            const float4 a = w0[m], b = w1[m];
            d0 += v.x * a.x + v.y * a.y + v.z * a.z + v.w * a.w;
            d1 += v.x * b.x + v.y * b.y + v.z * b.z + v.w * b.w;
            nj += v.x * v.x + v.y * v.y + v.z * v.z + v.w * v.w;
        }
        d0 += __shfl_xor(d0, 1); d0 += __shfl_xor(d0, 2);
        d1 += __shfl_xor(d1, 1); d1 += __shfl_xor(d1, 2);
        nj += __shfl_xor(nj, 1); nj += __shfl_xor(nj, 2);
        if (ch == 0) {
            const float r0 = fmaxf(n0 + nj - 2.f * d0, 0.f);
            const float r1 = fmaxf(n1 + nj - 2.f * d1, 0.f);
            drow[0][j] = (r0 == 0.f) ? EPSF : (sqrtf(r0 + EPSF) + EPSF);
            drow[1][j] = (r1 == 0.f) ? EPSF : (sqrtf(r1 + EPSF) + EPSF);
        }
    }
    __syncthreads();

    // positive lists (same label, j != anchor), then deterministic sort
    const int li0 = lab[i0], li1 = lab[i0 + 1];
    {
        const int j = t;
        if (lab[j] == li0 && j != i0)     { int q = atomicAdd(&npos[0], 1); poslist[0][q] = j; }
        if (lab[j] == li1 && j != i0 + 1) { int q = atomicAdd(&npos[1], 1); poslist[1][q] = j; }
    }
    __syncthreads();
    if (t < 2) {                // insertion sort (~8 entries)
        const int n = npos[t];
        for (int a2 = 1; a2 < n; ++a2) {
            int v = poslist[t][a2];
            int b2 = a2 - 1;
            while (b2 >= 0 && poslist[t][b2] > v) { poslist[t][b2 + 1] = poslist[t][b2]; --b2; }
            poslist[t][b2 + 1] = v;
        }
    }
    __syncthreads();

    // triplet accumulation: thread t owns negative candidate k = t
    const float bv = bias[0];
    float    lsum = 0.f;
    unsigned lcnt = 0u;
#pragma unroll
    for (int a = 0; a < 2; ++a) {
        const int    la = lab[i0 + a];
        const float* dr = &drow[a][0];
        if (lab[t] != la) {
            const float dik = dr[t];
            const int n = npos[a];
            for (int q = 0; q < n; ++q) {
                const float s = dr[poslist[a][q]] - dik + bv;   // poslist read = broadcast
                if (s > 0.f) { lsum += s; lcnt += (s > EPSF) ? 1u : 0u; }
            }
        }
    }

    // wave (64) shuffle reduce, then cross-wave
#pragma unroll
    for (int off = 32; off > 0; off >>= 1) {
        lsum += __shfl_down(lsum, off);
        lcnt += __shfl_down(lcnt, off);
    }
    if ((t & 63) == 0) { wsum[t >> 6] = lsum; wcnt[t >> 6] = lcnt; }
    __syncthreads();
    if (t == 0) {
        float s = 0.f; unsigned c = 0u;
#pragma unroll
        for (int w = 0; w < 8; ++w) { s += wsum[w]; c += wcnt[w]; }
        psum[blk] = s;
        pcnt[blk] = c;
    }
}

// ---------------------------------------------------------------------------
// Finalize: single 64-lane wave, fixed-order serial+shuffle reduce (determin.)
// ---------------------------------------------------------------------------
__global__ __launch_bounds__(64) void triplet_finalize(
    const float* __restrict__ psum,
    const unsigned* __restrict__ pcnt,
    float* __restrict__ out)
{
    const int t = threadIdx.x;
    float    s = psum[t] + psum[t + 64] + psum[t + 128] + psum[t + 192];
    unsigned c = pcnt[t] + pcnt[t + 64] + pcnt[t + 128] + pcnt[t + 192];
#pragma unroll
    for (int off = 32; off > 0; off >>= 1) {
        s += __shfl_down(s, off);
        c += __shfl_down(c, off);
    }
    if (t == 0) out[0] = s / ((float)c + 1e-16f);
}

extern "C" void kernel_launch(void* const* d_in, const int* in_sizes, int n_in,
                              void* d_out, int out_size, void* d_ws, size_t ws_size,
                              hipStream_t stream) {
    const float* X      = (const float*)d_in[0];
    const int*   labels = (const int*)d_in[1];
    const float* bias   = (const float*)d_in[2];
    float*       out    = (float*)d_out;

    float*    psum = (float*)d_ws;                        // 256 floats
    unsigned* pcnt = (unsigned*)((char*)d_ws + 256 * 4);  // 256 uints

    triplet_fused<<<256, 512, 0, stream>>>(X, labels, bias, psum, pcnt);
    triplet_finalize<<<1, 64, 0, stream>>>(psum, pcnt, out);
}